// Round 2
// 3118.577 us; speedup vs baseline: 1.0524x; 1.0524x over previous
//
#include <hip/hip_runtime.h>
#include <stdint.h>
#include <math.h>

typedef unsigned short u16;
typedef short short8 __attribute__((ext_vector_type(8)));
typedef float f32x4 __attribute__((ext_vector_type(4)));

typedef const __attribute__((address_space(1))) void* gptr_t;
typedef __attribute__((address_space(3))) void* lptr_t;

#define BQ 4
#define SQ 1024
#define DQ 1024
#define HQ 16
#define HDQ 64
#define LQ 8
#define VQ 50257
#define SCALE_Q 0.125f

__device__ __forceinline__ float bf2f(u16 u) {
    return __uint_as_float(((unsigned int)u) << 16);
}
__device__ __forceinline__ u16 f2bf(float f) {
    unsigned int u = __float_as_uint(f);
    unsigned int r = u + 0x7fffu + ((u >> 16) & 1u);
    return (u16)(r >> 16);
}

// ---------------------------------------------------------------- embed
__global__ __launch_bounds__(256) void embed_kernel(
    const int* __restrict__ tok, const float* __restrict__ wte,
    const float* __restrict__ wpe, float* __restrict__ x)
{
    int row = blockIdx.x;            // 0..4095 = b*1024+s
    int s = row & 1023;
    int t = tok[row];
    int c = threadIdx.x * 4;
    float4 a = *(const float4*)(wte + (size_t)t * DQ + c);
    float4 p = *(const float4*)(wpe + (size_t)s * DQ + c);
    float4 o; o.x = a.x + p.x; o.y = a.y + p.y; o.z = a.z + p.z; o.w = a.w + p.w;
    *(float4*)(x + (size_t)row * DQ + c) = o;
}

// ---------------------------------------------------------------- layernorm (fp32 in, bf16 out)
__global__ __launch_bounds__(256) void ln_kernel(
    const float* __restrict__ x, u16* __restrict__ out,
    const float* __restrict__ g, const float* __restrict__ bta,
    long xstride, long ostride)
{
    int row = blockIdx.x;
    int tid = threadIdx.x;
    const float* xr = x + (size_t)row * xstride;
    float4 v = *(const float4*)(xr + tid * 4);
    float s = v.x + v.y + v.z + v.w;
    float q = v.x * v.x + v.y * v.y + v.z * v.z + v.w * v.w;
    for (int o = 32; o > 0; o >>= 1) { s += __shfl_down(s, o); q += __shfl_down(q, o); }
    __shared__ float red[8];
    __shared__ float mr[2];
    int lane = tid & 63, w = tid >> 6;
    if (!lane) { red[w] = s; red[4 + w] = q; }
    __syncthreads();
    if (!tid) {
        float ts = red[0] + red[1] + red[2] + red[3];
        float tq = red[4] + red[5] + red[6] + red[7];
        float m = ts * (1.0f / 1024.0f);
        float var = tq * (1.0f / 1024.0f) - m * m;
        mr[0] = m; mr[1] = rsqrtf(var + 1e-5f);
    }
    __syncthreads();
    float m = mr[0], r = mr[1];
    int c = tid * 4;
    float vv[4] = { v.x, v.y, v.z, v.w };
    u16* orow = out + (size_t)row * ostride;
    #pragma unroll
    for (int j = 0; j < 4; j++)
        orow[c + j] = f2bf((vv[j] - m) * r * g[c + j] + bta[c + j]);
}

// ---------------------------------------------------------------- weight transpose fp32 [R][C] -> bf16 [C][R], batched over layers (z)
__global__ __launch_bounds__(256) void transpose_w(
    const float* __restrict__ src, u16* __restrict__ dst, int R, int C,
    long src_lstride, long dst_lstride)
{
    int lyr = blockIdx.z;
    src += (size_t)lyr * src_lstride;
    dst += (size_t)lyr * dst_lstride;
    __shared__ float t[32][33];
    int c0 = blockIdx.x * 32, r0 = blockIdx.y * 32;
    int tx = threadIdx.x & 31, ty = threadIdx.x >> 5;
    #pragma unroll
    for (int i = 0; i < 4; i++) {
        int r = r0 + ty + i * 8;
        t[ty + i * 8][tx] = src[(size_t)r * C + c0 + tx];
    }
    __syncthreads();
    #pragma unroll
    for (int i = 0; i < 4; i++) {
        int c = c0 + ty + i * 8;
        dst[(size_t)c * R + r0 + tx] = f2bf(t[tx][ty + i * 8]);
    }
}

// ---------------------------------------------------------------- V transpose: qkv[b][s][2048+h*64+d] -> VT[bh][d][s]  (64 d-rows)
__global__ __launch_bounds__(256) void v_transpose(
    const u16* __restrict__ qkv, u16* __restrict__ VT)
{
    int bh = blockIdx.y; int b = bh >> 4, h = bh & 15;
    int s0 = blockIdx.x * 64;
    __shared__ u16 t[64][65];
    int tid = threadIdx.x;
    #pragma unroll
    for (int i = 0; i < 16; i++) {
        int idx = tid + i * 256;
        int s = idx >> 6, d = idx & 63;
        t[s][d] = qkv[((size_t)(b * SQ + s0 + s)) * 3072 + 2048 + h * 64 + d];
    }
    __syncthreads();
    #pragma unroll
    for (int i = 0; i < 16; i++) {
        int idx = tid + i * 256;
        int d = idx >> 6, s = idx & 63;
        VT[((size_t)bh * 64 + d) * SQ + s0 + s] = t[s][d];
    }
}

// ---------------------------------------------------------------- fused flash attention
__global__ __launch_bounds__(256, 2) void flash_attn(
    const u16* __restrict__ qkv, const u16* __restrict__ VT, u16* __restrict__ attn)
{
    __shared__ char smem[65536];
    char* Pb = smem;              // 32 KB: swizzled P tile [128 q][256B]; Q tile at start
    char* Kb = smem + 32768;      // 16 KB: K tile [128 ks][128B]
    char* Vb = smem + 49152;      // 16 KB: VT tile [64 d][256B]
    float* abuf = (float*)Kb;     // 512 B alias — written only after K consumed

    const int tid = threadIdx.x;
    const int l = tid & 63, w = tid >> 6;
    const int lhi = l >> 4, llo = l & 15;
    const int bh = blockIdx.x; const int b = bh >> 4, h = bh & 15;
    const int qt = blockIdx.y;
    const int q0g = qt * 128;

    #pragma unroll
    for (int i = 0; i < 4; i++) {
        int off = (w * 4 + i) * 1024 + l * 16;
        int q = off >> 7, db = (off & 127) >> 1;
        const u16* g = qkv + (size_t)(b * 1024 + q0g + q) * 3072 + h * 64 + db;
        __builtin_amdgcn_global_load_lds((gptr_t)g, (lptr_t)(Pb + (w * 4 + i) * 1024), 16, 0, 0);
    }
    asm volatile("s_waitcnt vmcnt(0)" ::: "memory");

    short8 qf[2][2];
    #pragma unroll
    for (int mt = 0; mt < 2; mt++)
        #pragma unroll
        for (int ks = 0; ks < 2; ks++)
            qf[mt][ks] = *(const short8*)(Pb + (w * 32 + mt * 16 + llo) * 128 + (ks * 32 + lhi * 8) * 2);

    f32x4 oacc[4][2];
    f32x4 zero = { 0.f, 0.f, 0.f, 0.f };
    #pragma unroll
    for (int i = 0; i < 4; i++) { oacc[i][0] = zero; oacc[i][1] = zero; }
    float mrow[2][4], lrow[2][4];
    #pragma unroll
    for (int mt = 0; mt < 2; mt++)
        #pragma unroll
        for (int r = 0; r < 4; r++) { mrow[mt][r] = -1e30f; lrow[mt][r] = 0.f; }

    for (int kt = 0; kt <= qt; kt++) {
        const int kt0 = kt * 128;
        __syncthreads();
        #pragma unroll
        for (int i = 0; i < 4; i++) {
            int off = (w * 4 + i) * 1024 + l * 16;
            int ks = off >> 7, db = (off & 127) >> 1;
            const u16* g = qkv + (size_t)(b * 1024 + kt0 + ks) * 3072 + 1024 + h * 64 + db;
            __builtin_amdgcn_global_load_lds((gptr_t)g, (lptr_t)(Kb + (w * 4 + i) * 1024), 16, 0, 0);
        }
        #pragma unroll
        for (int i = 0; i < 4; i++) {
            int off = (w * 4 + i) * 1024 + l * 16;
            int d = off >> 8, kb = (off & 255) >> 1;
            const u16* g = VT + ((size_t)(bh * 64 + d)) * 1024 + kt0 + kb;
            __builtin_amdgcn_global_load_lds((gptr_t)g, (lptr_t)(Vb + (w * 4 + i) * 1024), 16, 0, 0);
        }
        asm volatile("s_waitcnt vmcnt(0)" ::: "memory");
        __syncthreads();

        f32x4 s[2][8];
        #pragma unroll
        for (int mt = 0; mt < 2; mt++)
            #pragma unroll
            for (int nt = 0; nt < 8; nt++) s[mt][nt] = zero;
        #pragma unroll
        for (int kst = 0; kst < 2; kst++)
            #pragma unroll
            for (int nt = 0; nt < 8; nt++) {
                short8 kf = *(const short8*)(Kb + (nt * 16 + llo) * 128 + (kst * 32 + lhi * 8) * 2);
                s[0][nt] = __builtin_amdgcn_mfma_f32_16x16x32_bf16(qf[0][kst], kf, s[0][nt], 0, 0, 0);
                s[1][nt] = __builtin_amdgcn_mfma_f32_16x16x32_bf16(qf[1][kst], kf, s[1][nt], 0, 0, 0);
            }
        __syncthreads();

        if (kt == qt) {
            #pragma unroll
            for (int mt = 0; mt < 2; mt++)
                #pragma unroll
                for (int nt = 0; nt < 8; nt++)
                    #pragma unroll
                    for (int r = 0; r < 4; r++) {
                        int qloc = w * 32 + mt * 16 + lhi * 4 + r;
                        int ksloc = nt * 16 + llo;
                        if (ksloc > qloc) s[mt][nt][r] = -1e30f;
                    }
        }

        #pragma unroll
        for (int mt = 0; mt < 2; mt++) {
            #pragma unroll
            for (int r = 0; r < 4; r++) {
                float v = s[mt][0][r];
                #pragma unroll
                for (int nt = 1; nt < 8; nt++) v = fmaxf(v, s[mt][nt][r]);
                v = fmaxf(v, __shfl_xor(v, 1));
                v = fmaxf(v, __shfl_xor(v, 2));
                v = fmaxf(v, __shfl_xor(v, 4));
                v = fmaxf(v, __shfl_xor(v, 8));
                float mn = fmaxf(mrow[mt][r], v);
                float alpha = __expf((mrow[mt][r] - mn) * SCALE_Q);
                mrow[mt][r] = mn;
                int qrow = w * 32 + mt * 16 + lhi * 4 + r;
                int qm = qrow & 15;
                float rs = 0.f;
                #pragma unroll
                for (int nt = 0; nt < 8; nt++) {
                    float p = __expf((s[mt][nt][r] - mn) * SCALE_Q);
                    rs += p;
                    int phys = (nt * 2 + (llo >> 3)) ^ qm;
                    *(u16*)(Pb + qrow * 256 + phys * 16 + (l & 7) * 2) = f2bf(p);
                }
                rs += __shfl_xor(rs, 1);
                rs += __shfl_xor(rs, 2);
                rs += __shfl_xor(rs, 4);
                rs += __shfl_xor(rs, 8);
                lrow[mt][r] = lrow[mt][r] * alpha + rs;
                if (llo == 0) abuf[w * 32 + mt * 16 + lhi * 4 + r] = alpha;
            }
        }

        float a0 = abuf[w * 32 + llo];
        float a1 = abuf[w * 32 + 16 + llo];
        #pragma unroll
        for (int dmt = 0; dmt < 4; dmt++) { oacc[dmt][0] *= a0; oacc[dmt][1] *= a1; }

        #pragma unroll
        for (int kst = 0; kst < 4; kst++) {
            short8 pf[2];
            #pragma unroll
            for (int qnt = 0; qnt < 2; qnt++) {
                int q = w * 32 + qnt * 16 + llo;
                int phys = (kst * 4 + lhi) ^ (q & 15);
                pf[qnt] = *(const short8*)(Pb + q * 256 + phys * 16);
            }
            #pragma unroll
            for (int dmt = 0; dmt < 4; dmt++) {
                short8 vf = *(const short8*)(Vb + (dmt * 16 + llo) * 256 + (kst * 32 + lhi * 8) * 2);
                oacc[dmt][0] = __builtin_amdgcn_mfma_f32_16x16x32_bf16(vf, pf[0], oacc[dmt][0], 0, 0, 0);
                oacc[dmt][1] = __builtin_amdgcn_mfma_f32_16x16x32_bf16(vf, pf[1], oacc[dmt][1], 0, 0, 0);
            }
        }
    }

    if (llo == 0) {
        #pragma unroll
        for (int mt = 0; mt < 2; mt++)
            #pragma unroll
            for (int r = 0; r < 4; r++)
                abuf[w * 32 + mt * 16 + lhi * 4 + r] = lrow[mt][r];
    }
    float li0 = 1.0f / abuf[w * 32 + llo];
    float li1 = 1.0f / abuf[w * 32 + 16 + llo];
    #pragma unroll
    for (int dmt = 0; dmt < 4; dmt++) {
        #pragma unroll
        for (int qnt = 0; qnt < 2; qnt++) {
            int q = q0g + w * 32 + qnt * 16 + llo;
            int d0 = dmt * 16 + lhi * 4;
            float li = qnt ? li1 : li0;
            u16 e0 = f2bf(oacc[dmt][qnt][0] * li);
            u16 e1 = f2bf(oacc[dmt][qnt][1] * li);
            u16 e2 = f2bf(oacc[dmt][qnt][2] * li);
            u16 e3 = f2bf(oacc[dmt][qnt][3] * li);
            uint2 pk;
            pk.x = (unsigned)e0 | ((unsigned)e1 << 16);
            pk.y = (unsigned)e2 | ((unsigned)e3 << 16);
            *(uint2*)(attn + (size_t)(b * 1024 + q) * 1024 + h * 64 + d0) = pk;
        }
    }
}

// ---------------------------------------------------------------- legacy 128x128 GEMM (kept for wo projection)
template<int MODE>
__global__ __launch_bounds__(256) void gemm128(
    const u16* __restrict__ A, const u16* __restrict__ Bt, void* __restrict__ Cv,
    const float* __restrict__ bias, int K, int lda, int ldb, int ldc,
    int Nvalid, float alpha, int innerB,
    long sAo, long sAi, long sBo, long sBi, long sCo, long sCi)
{
    __shared__ char smem[16384];
    const int tid = threadIdx.x;
    const int lane = tid & 63;
    const int wave = tid >> 6;
    const int wm = wave >> 1, wn = wave & 1;

    const int z = blockIdx.z;
    const long zo = z / innerB, zi = z % innerB;
    A += zo * sAo + zi * sAi;
    Bt += zo * sBo + zi * sBi;
    const long coff = zo * sCo + zi * sCi;

    const int m0 = blockIdx.y * 128, n0 = blockIdx.x * 128;

    const int r0 = tid >> 2, c0 = (tid & 3) * 8;
    const int r1 = r0 + 64;
    char* ldsA0 = smem + wave * 1024;
    char* ldsA1 = smem + 4096 + wave * 1024;
    char* ldsB0 = smem + 8192 + wave * 1024;
    char* ldsB1 = smem + 8192 + 4096 + wave * 1024;

    f32x4 acc[16];
    f32x4 zero = { 0.f, 0.f, 0.f, 0.f };
    #pragma unroll
    for (int i = 0; i < 16; i++) acc[i] = zero;

    int aoff[4], boff[4];
    #pragma unroll
    for (int t = 0; t < 4; t++) {
        aoff[t] = ((wm * 64 + t * 16 + (lane & 15)) * 32 + (lane >> 4) * 8) * 2;
        boff[t] = 8192 + ((wn * 64 + t * 16 + (lane & 15)) * 32 + (lane >> 4) * 8) * 2;
    }

    for (int k0 = 0; k0 < K; k0 += 32) {
        __syncthreads();
        const u16* ga0 = A + (size_t)(m0 + r0) * lda + k0 + c0;
        const u16* ga1 = A + (size_t)(m0 + r1) * lda + k0 + c0;
        const u16* gb0 = Bt + (size_t)(n0 + r0) * ldb + k0 + c0;
        const u16* gb1 = Bt + (size_t)(n0 + r1) * ldb + k0 + c0;
        __builtin_amdgcn_global_load_lds((gptr_t)ga0, (lptr_t)ldsA0, 16, 0, 0);
        __builtin_amdgcn_global_load_lds((gptr_t)ga1, (lptr_t)ldsA1, 16, 0, 0);
        __builtin_amdgcn_global_load_lds((gptr_t)gb0, (lptr_t)ldsB0, 16, 0, 0);
        __builtin_amdgcn_global_load_lds((gptr_t)gb1, (lptr_t)ldsB1, 16, 0, 0);
        asm volatile("s_waitcnt vmcnt(0)" ::: "memory");
        __syncthreads();
        short8 af[4], bfr[4];
        #pragma unroll
        for (int t = 0; t < 4; t++) {
            af[t] = *(const short8*)(smem + aoff[t]);
            bfr[t] = *(const short8*)(smem + boff[t]);
        }
        #pragma unroll
        for (int mt = 0; mt < 4; mt++)
            #pragma unroll
            for (int nt = 0; nt < 4; nt++)
                acc[mt * 4 + nt] = __builtin_amdgcn_mfma_f32_16x16x32_bf16(
                    af[mt], bfr[nt], acc[mt * 4 + nt], 0, 0, 0);
    }

    const int cn = lane & 15, rq = lane >> 4;
    #pragma unroll
    for (int mt = 0; mt < 4; mt++) {
        #pragma unroll
        for (int nt = 0; nt < 4; nt++) {
            #pragma unroll
            for (int r = 0; r < 4; r++) {
                int m = m0 + wm * 64 + mt * 16 + rq * 4 + r;
                int n = n0 + wn * 64 + nt * 16 + cn;
                if (n < Nvalid) {
                    float bv = (bias && (MODE != 3 || zo == 0)) ? bias[n] : 0.f;
                    float v = acc[mt * 4 + nt][r] * alpha + bv;
                    if (MODE == 1) v = 0.5f * v * (1.0f + erff(v * 0.70710678118654752f));
                    if (MODE == 2) {
                        float* C = (float*)Cv + coff;
                        C[(size_t)m * ldc + n] += v;
                    } else if (MODE == 3) {
                        float* C = (float*)Cv + coff;
                        atomicAdd(&C[(size_t)m * ldc + n], v);
                    } else {
                        u16* C = (u16*)Cv + coff;
                        C[(size_t)m * ldc + n] = f2bf(v);
                    }
                }
            }
        }
    }
}

// ---------------------------------------------------------------- 256x256 8-phase GEMM (T2+T3+T4+T5 template)
// C[M,N] = A[M,K](bf16) * Bt[N,K](bf16)^T.  BK=64, 8 waves (2M x 4N),
// 128 KiB LDS double-buffered, st_16x32 swizzle (inverse-swz global source +
// swz ds_read, linear global_load_lds dest), counted vmcnt(6), raw s_barrier.
//   tile u ph1: issue (u+1, B-h0)   ph2: (u+2, A-h0)   ph3: (u+2, B-h1)
//   ph4: (u+2, A-h1) + s_waitcnt vmcnt(6)
__device__ __forceinline__ short8 ldsfrag(const char* tbase, int row, int cb) {
    int off = row * 128 + cb;
    off ^= ((off >> 9) & 1) << 5;      // st_16x32
    return *(const short8*)(tbase + off);
}

__device__ __forceinline__ void issue_half(
    const u16* __restrict__ A, const u16* __restrict__ Bt,
    char* smem, int m0, int n0, int lda, int ldb,
    int t, int hi, int b, int w, int lane)
{
    // hi: 0=A-h0 1=A-h1 2=B-h0 3=B-h1 ; b = dest buffer
    char* base = smem + (b << 16) + ((hi >> 1) << 15) + ((hi & 1) << 14);
    const u16* src; int ld;
    int r0 = (hi & 1) << 7;
    if (hi < 2) { src = A + (size_t)(m0 + r0) * lda + t * 64; ld = lda; }
    else        { src = Bt + (size_t)(n0 + r0) * ldb + t * 64; ld = ldb; }
    #pragma unroll
    for (int j = 0; j < 2; j++) {
        int p = (j * 8 + w) * 1024 + lane * 16;          // linear LDS dest byte
        int rr = p >> 7;                                  // local row (128B rows)
        int lcb = (p & 127) ^ (((p >> 9) & 1) << 5);      // inverse-swz source col
        __builtin_amdgcn_global_load_lds(
            (gptr_t)(src + (size_t)rr * ld + (lcb >> 1)),
            (lptr_t)(base + (j * 8 + w) * 1024), 16, 0, 0);
    }
}

template<int MODE>
__global__ __launch_bounds__(512, 2) void gemm256(
    const u16* __restrict__ A, const u16* __restrict__ Bt, void* __restrict__ Cv,
    const float* __restrict__ bias, int K, int lda, int ldb, int ldc,
    float alpha, long sAo, long sBo)
{
    __shared__ char smem[131072];
    const int tid = threadIdx.x;
    const int lane = tid & 63;
    const int w = tid >> 6;              // 0..7
    const int wm = w >> 2, wn = w & 3;   // 2 x 4
    const int l15 = lane & 15, lhi = lane >> 4;

    const int z = blockIdx.z;
    A += (size_t)z * sAo;
    Bt += (size_t)z * sBo;

    // bijective XCD swizzle (m204)
    int flat = blockIdx.y * gridDim.x + blockIdx.x;
    {
        const int nwg = gridDim.x * gridDim.y;
        int q = nwg >> 3, r = nwg & 7;
        int xcd = flat & 7, loc = flat >> 3;
        flat = (xcd < r ? xcd * (q + 1) : r * (q + 1) + (xcd - r) * q) + loc;
    }
    const int n0 = (flat % gridDim.x) * 256;
    const int m0 = (flat / gridDim.x) * 256;

    const int NT = K >> 6;

    f32x4 acc[8][4];
    f32x4 zero = { 0.f, 0.f, 0.f, 0.f };
    #pragma unroll
    for (int i = 0; i < 8; i++)
        #pragma unroll
        for (int j = 0; j < 4; j++) acc[i][j] = zero;

    // prologue: tile0 (all 4 halves) -> buf0; tile1 {A-h0, B-h1, A-h1} -> buf1
    {
        int t1p = (NT > 1) ? 1 : 0;
        issue_half(A, Bt, smem, m0, n0, lda, ldb, 0, 0, 0, w, lane);
        issue_half(A, Bt, smem, m0, n0, lda, ldb, 0, 1, 0, w, lane);
        issue_half(A, Bt, smem, m0, n0, lda, ldb, 0, 2, 0, w, lane);
        issue_half(A, Bt, smem, m0, n0, lda, ldb, 0, 3, 0, w, lane);
        issue_half(A, Bt, smem, m0, n0, lda, ldb, t1p, 0, 1, w, lane);
        issue_half(A, Bt, smem, m0, n0, lda, ldb, t1p, 3, 1, w, lane);
        issue_half(A, Bt, smem, m0, n0, lda, ldb, t1p, 1, 1, w, lane);
    }
    asm volatile("s_waitcnt vmcnt(6)" ::: "memory");
    __builtin_amdgcn_s_barrier();

    for (int u = 0; u < NT; ++u) {
        const int b = u & 1;
        const int b1 = b ^ 1;
        char* Ab = smem + (b << 16);
        char* Bb = Ab + 32768;
        const int t1 = (u + 1 < NT) ? u + 1 : NT - 1;
        const int t2 = (u + 2 < NT) ? u + 2 : NT - 1;

        short8 af[4][2], bfr[2][2];

        // ---------- phase 1: m-half0 x n-half0 (12 ds_read)
        #pragma unroll
        for (int mt = 0; mt < 4; mt++)
            #pragma unroll
            for (int ks = 0; ks < 2; ks++)
                af[mt][ks] = ldsfrag(Ab, wm * 64 + mt * 16 + l15, ks * 64 + lhi * 16);
        #pragma unroll
        for (int nt = 0; nt < 2; nt++)
            #pragma unroll
            for (int ks = 0; ks < 2; ks++)
                bfr[nt][ks] = ldsfrag(Bb, wn * 32 + nt * 16 + l15, ks * 64 + lhi * 16);
        issue_half(A, Bt, smem, m0, n0, lda, ldb, t1, 2, b1, w, lane);
        __builtin_amdgcn_s_barrier();
        asm volatile("s_waitcnt lgkmcnt(0)" ::: "memory");
        __builtin_amdgcn_s_setprio(1);
        #pragma unroll
        for (int mt = 0; mt < 4; mt++)
            #pragma unroll
            for (int nt = 0; nt < 2; nt++)
                #pragma unroll
                for (int ks = 0; ks < 2; ks++)
                    acc[mt][nt] = __builtin_amdgcn_mfma_f32_16x16x32_bf16(
                        af[mt][ks], bfr[nt][ks], acc[mt][nt], 0, 0, 0);
        __builtin_amdgcn_s_setprio(0);
        __builtin_amdgcn_s_barrier();

        // ---------- phase 2: m-half0 x n-half1 (4 ds_read, af reused)
        #pragma unroll
        for (int nt = 0; nt < 2; nt++)
            #pragma unroll
            for (int ks = 0; ks < 2; ks++)
                bfr[nt][ks] = ldsfrag(Bb, 128 + wn * 32 + nt * 16 + l15, ks * 64 + lhi * 16);
        issue_half(A, Bt, smem, m0, n0, lda, ldb, t2, 0, b, w, lane);
        __builtin_amdgcn_s_barrier();
        asm volatile("s_waitcnt lgkmcnt(0)" ::: "memory");
        __builtin_amdgcn_s_setprio(1);
        #pragma unroll
        for (int mt = 0; mt < 4; mt++)
            #pragma unroll
            for (int nt = 0; nt < 2; nt++)
                #pragma unroll
                for (int ks = 0; ks < 2; ks++)
                    acc[mt][2 + nt] = __builtin_amdgcn_mfma_f32_16x16x32_bf16(
                        af[mt][ks], bfr[nt][ks], acc[mt][2 + nt], 0, 0, 0);
        __builtin_amdgcn_s_setprio(0);
        __builtin_amdgcn_s_barrier();

        // ---------- phase 3: m-half1 x n-half1 (8 ds_read, bfr reused)
        #pragma unroll
        for (int mt = 0; mt < 4; mt++)
            #pragma unroll
            for (int ks = 0; ks < 2; ks++)
                af[mt][ks] = ldsfrag(Ab, 128 + wm * 64 + mt * 16 + l15, ks * 64 + lhi * 16);
        issue_half(A, Bt, smem, m0, n0, lda, ldb, t2, 3, b, w, lane);
        __builtin_amdgcn_s_barrier();
        asm volatile("s_waitcnt lgkmcnt(0)" ::: "memory");
        __builtin_amdgcn_s_setprio(1);
        #pragma unroll
        for (int mt = 0; mt < 4; mt++)
            #pragma unroll
            for (int nt = 0; nt < 2; nt++)
                #pragma unroll
                for (int ks = 0; ks < 2; ks++)
                    acc[4 + mt][2 + nt] = __builtin_amdgcn_mfma_f32_16x16x32_bf16(
                        af[mt][ks], bfr[nt][ks], acc[4 + mt][2 + nt], 0, 0, 0);
        __builtin_amdgcn_s_setprio(0);
        __builtin_amdgcn_s_barrier();

        // ---------- phase 4: m-half1 x n-half0 (4 ds_read, af reused) + vmcnt(6)
        #pragma unroll
        for (int nt = 0; nt < 2; nt++)
            #pragma unroll
            for (int ks = 0; ks < 2; ks++)
                bfr[nt][ks] = ldsfrag(Bb, wn * 32 + nt * 16 + l15, ks * 64 + lhi * 16);
        issue_half(A, Bt, smem, m0, n0, lda, ldb, t2, 1, b, w, lane);
        asm volatile("s_waitcnt vmcnt(6)" ::: "memory");
        __builtin_amdgcn_s_barrier();
        asm volatile("s_waitcnt lgkmcnt(0)" ::: "memory");
        __builtin_amdgcn_s_setprio(1);
        #pragma unroll
        for (int mt = 0; mt < 4; mt++)
            #pragma unroll
            for (int nt = 0; nt < 2; nt++)
                #pragma unroll
                for (int ks = 0; ks < 2; ks++)
                    acc[4 + mt][nt] = __builtin_amdgcn_mfma_f32_16x16x32_bf16(
                        af[mt][ks], bfr[nt][ks], acc[4 + mt][nt], 0, 0, 0);
        __builtin_amdgcn_s_setprio(0);
        __builtin_amdgcn_s_barrier();
    }
    asm volatile("s_waitcnt vmcnt(0)" ::: "memory");

    // ---------- epilogue
    const int rq = lane >> 4, cn = lane & 15;
    #pragma unroll
    for (int mt = 0; mt < 8; mt++) {
        int mrow = m0 + ((mt < 4) ? wm * 64 + mt * 16 : 128 + wm * 64 + (mt - 4) * 16) + rq * 4;
        #pragma unroll
        for (int nt = 0; nt < 4; nt++) {
            int ncol = n0 + ((nt < 2) ? wn * 32 + nt * 16 : 128 + wn * 32 + (nt - 2) * 16) + cn;
            float bv = (bias && (MODE != 3 || z == 0)) ? bias[ncol] : 0.f;
            #pragma unroll
            for (int r = 0; r < 4; r++) {
                float v = acc[mt][nt][r] * alpha + bv;
                if (MODE == 1) v = 0.5f * v * (1.0f + erff(v * 0.70710678118654752f));
                if (MODE == 2) {
                    float* C = (float*)Cv;
                    C[(size_t)(mrow + r) * ldc + ncol] += v;
                } else if (MODE == 3) {
                    float* C = (float*)Cv;
                    atomicAdd(&C[(size_t)(mrow + r) * ldc + ncol], v);
                } else {
                    u16* C = (u16*)Cv;
                    C[(size_t)(mrow + r) * ldc + ncol] = f2bf(v);
                }
            }
        }
    }
}

// ---------------------------------------------------------------- head: out[b][v] = xf[b][:] . w_head[:, v]
__global__ __launch_bounds__(256) void head_kernel(
    const u16* __restrict__ xf, const float* __restrict__ wh, float* __restrict__ out)
{
    __shared__ float xs[4 * 1024];
    int tid = threadIdx.x;
    #pragma unroll
    for (int i = 0; i < 16; i++) {
        int idx = tid + i * 256;
        xs[idx] = bf2f(xf[idx]);
    }
    __syncthreads();
    int v = blockIdx.x * 256 + tid;
    if (v >= VQ) return;
    float a0 = 0.f, a1 = 0.f, a2 = 0.f, a3 = 0.f;
    for (int k = 0; k < 1024; k++) {
        float w = wh[(size_t)k * VQ + v];
        a0 += xs[k] * w;
        a1 += xs[1024 + k] * w;
        a2 += xs[2048 + k] * w;
        a3 += xs[3072 + k] * w;
    }
    out[v] = a0;
    out[VQ + v] = a1;
    out[2 * (size_t)VQ + v] = a2;
    out[3 * (size_t)VQ + v] = a3;
}

// ================================================================ host
extern "C" void kernel_launch(void* const* d_in, const int* in_sizes, int n_in,
                              void* d_out, int out_size, void* d_ws, size_t ws_size,
                              hipStream_t stream)
{
    const int*   tokens = (const int*)d_in[0];
    const float* wte  = (const float*)d_in[1];
    const float* wpe  = (const float*)d_in[2];
    const float* ln1g = (const float*)d_in[3];
    const float* ln1b = (const float*)d_in[4];
    const float* wqkv = (const float*)d_in[5];
    const float* bqkv = (const float*)d_in[6];
    const float* wo   = (const float*)d_in[7];
    const float* bo   = (const float*)d_in[8];
    const float* ln2g = (const float*)d_in[9];
    const float* ln2b = (const float*)d_in[10];
    const float* w1   = (const float*)d_in[11];
    const float* b1   = (const float*)d_in[12];
    const float* w2   = (const float*)d_in[13];
    const float* b2   = (const float*)d_in[14];
    const float* lnfg = (const float*)d_in[15];
    const float* lnfb = (const float*)d_in[16];
    const float* whead= (const float*)d_in[17];
    float* out = (float*)d_out;

    uint8_t* p = (uint8_t*)d_ws;
    u16*  wqkvT = (u16*)p;  p += (size_t)LQ * 3072 * 1024 * 2;
    u16*  woT   = (u16*)p;  p += (size_t)LQ * 1024 * 1024 * 2;
    u16*  w1T   = (u16*)p;  p += (size_t)LQ * 4096 * 1024 * 2;
    u16*  w2T   = (u16*)p;  p += (size_t)LQ * 1024 * 4096 * 2;
    float* x    = (float*)p; p += (size_t)4096 * 1024 * 4;
    u16*  h     = (u16*)p;  p += (size_t)4096 * 1024 * 2;
    u16*  qkv   = (u16*)p;  p += (size_t)4096 * 3072 * 2;
    u16*  VT    = (u16*)p;  p += (size_t)64 * 64 * 1024 * 2;
    u16*  attn  = (u16*)p;  p += (size_t)4096 * 1024 * 2;
    u16*  hid   = (u16*)p;  p += (size_t)4096 * 4096 * 2;
    u16*  xf    = (u16*)p;  p += (size_t)4096 * 2;

    embed_kernel<<<4096, 256, 0, stream>>>(tokens, wte, wpe, x);

    // all weight transposes hoisted + batched over layers (once per invocation)
    transpose_w<<<dim3(96, 32, LQ), 256, 0, stream>>>(wqkv, wqkvT, 1024, 3072, 3145728L, 3145728L);
    transpose_w<<<dim3(32, 32, LQ), 256, 0, stream>>>(wo,   woT,   1024, 1024, 1048576L, 1048576L);
    transpose_w<<<dim3(128, 32, LQ), 256, 0, stream>>>(w1,  w1T,   1024, 4096, 4194304L, 4194304L);
    transpose_w<<<dim3(32, 128, LQ), 256, 0, stream>>>(w2,  w2T,   4096, 1024, 4194304L, 4194304L);

    for (int l = 0; l < LQ; l++) {
        u16* wqkvTl = wqkvT + (size_t)l * 3072 * 1024;
        u16* woTl   = woT   + (size_t)l * 1024 * 1024;
        u16* w1Tl   = w1T   + (size_t)l * 4096 * 1024;
        u16* w2Tl   = w2T   + (size_t)l * 1024 * 4096;

        // ---- attention
        ln_kernel<<<4096, 256, 0, stream>>>(x, h, ln1g + l * 1024, ln1b + l * 1024, 1024, 1024);
        // qkv = h @ Wqkv + b : M=4096 N=3072 K=1024
        gemm256<0><<<dim3(12, 16, 1), 512, 0, stream>>>(h, wqkvTl, qkv, bqkv + l * 3072,
            1024, 1024, 1024, 3072, 1.0f, 0, 0);
        v_transpose<<<dim3(16, 64), 256, 0, stream>>>(qkv, VT);
        flash_attn<<<dim3(64, 8), 256, 0, stream>>>(qkv, VT, attn);
        // x += attn @ Wo + bo : M=4096 N=1024 K=1024, fp32 residual
        gemm128<2><<<dim3(8, 32, 1), 256, 0, stream>>>(attn, woTl, x, bo + l * 1024,
            1024, 1024, 1024, 1024, 1024, 1.0f, 1, 0, 0, 0, 0, 0, 0);
        // ---- mlp
        ln_kernel<<<4096, 256, 0, stream>>>(x, h, ln2g + l * 1024, ln2b + l * 1024, 1024, 1024);
        // hid = gelu(h @ W1 + b1) : M=4096 N=4096 K=1024
        gemm256<1><<<dim3(16, 16, 1), 512, 0, stream>>>(h, w1Tl, hid, b1 + l * 4096,
            1024, 1024, 1024, 4096, 1.0f, 0, 0);
        // x += hid @ W2 + b2 : M=4096 N=1024 K=4096, split-K=4 fp32 atomic residual
        gemm256<3><<<dim3(4, 16, 4), 512, 0, stream>>>(hid, w2Tl, x, b2 + l * 1024,
            1024, 4096, 4096, 1024, 1.0f, 1024, 1024);
    }

    // final LN on the 4 last-token rows, then head
    ln_kernel<<<4, 256, 0, stream>>>(x + (size_t)1023 * 1024, xf, lnfg, lnfb, 1048576, 1024);
    head_kernel<<<197, 256, 0, stream>>>(xf, whead, out);
}